// Round 5
// baseline (1150.034 us; speedup 1.0000x reference)
//
#include <hip/hip_runtime.h>
#include <hip/hip_bf16.h>
#include <stdint.h>

#define M_DIM 4096   // B*S
#define K_DIM 2048   // H
#define N_DIM 8192   // OUT
#define NT 96        // K' = 3*2048 / 64

typedef __attribute__((ext_vector_type(4))) float f32x4;
typedef __attribute__((ext_vector_type(8))) __bf16 bf16x8;

typedef __attribute__((address_space(1))) const unsigned int g_u32_t;
typedef __attribute__((address_space(3))) unsigned int lds_u32_t;

static __device__ __forceinline__ void gload16(const void* g, void* l) {
  __builtin_amdgcn_global_load_lds((g_u32_t*)g, (lds_u32_t*)l, 16, 0, 0);
}

#define BOUNDF ((float)(-2.053748910631823))

__device__ __forceinline__ unsigned char gate_passed(float y1v, float sqv,
                                                     float sw, float sb) {
  float cm = y1v / 32.0f * sw + sb;
  float cv = (sqv / 32.0f - cm * cm) * sw * sw;
  float ts = cm / sqrtf(cv / 32.0f);
  return (ts < BOUNDF) ? (unsigned char)1 : (unsigned char)0;
}

// ---------------- split fp32 -> bf16 hi/lo, plus packed E-prefix copy ----------------
__global__ void split_bf16_kernel(const float* __restrict__ src,
                                  unsigned short* __restrict__ hi,
                                  unsigned short* __restrict__ lo,
                                  float* __restrict__ packed_e,
                                  int n4) {
  int i = blockIdx.x * blockDim.x + threadIdx.x;
  int stride = gridDim.x * blockDim.x;
  for (; i < n4; i += stride) {
    float4 v = reinterpret_cast<const float4*>(src)[i];
    int col4 = i & (K_DIM / 4 - 1);
    if (col4 < 8) {
      int row = i >> 9;
      reinterpret_cast<float4*>(packed_e)[row * 8 + col4] = v;
    }
    float xs[4] = {v.x, v.y, v.z, v.w};
    unsigned short hb[4], lb[4];
#pragma unroll
    for (int j = 0; j < 4; ++j) {
      __hip_bfloat16 t = __float2bfloat16(xs[j]);
      unsigned short tb = *reinterpret_cast<unsigned short*>(&t);
      float hf = __uint_as_float(((unsigned)tb) << 16);
      __hip_bfloat16 t2 = __float2bfloat16(xs[j] - hf);
      hb[j] = tb;
      lb[j] = *reinterpret_cast<unsigned short*>(&t2);
    }
    reinterpret_cast<ushort4*>(hi)[i] = make_ushort4(hb[0], hb[1], hb[2], hb[3]);
    reinterpret_cast<ushort4*>(lo)[i] = make_ushort4(lb[0], lb[1], lb[2], lb[3]);
  }
}

// ---------------- main GEMM: 256x256, 4-phase/K-tile interleaved pipeline ----------------
// K' regions: t in [0,32): A=xh B=wh; [32,64): A=xh B=wl; [64,96): A=xl B=wh.
// LDS 128KB: [slotA0 32K][slotA1 32K][slotB0 32K][slotB1 32K]; panel = 256 rows x 64 k bf16.
// Panel layout: byte(row,ks) = (row>>3)*1024 + ks*128 + (row&7)*16, ks = k/8 in [0,8).
//   -> ds_read_b128 frag reads are bank-conflict-free (each 8-lane cluster sweeps 128B).
// Staging: gload16 linear dest L = r*8192 + tid*16; inverse map row = r*64+(tid>>6)*8+(tid&7),
//   ks = (tid>>3)&7 -> per-lane pre-permuted global source (rule #21: both-sides-or-neither).

#define STAGE_A(TT)                                                            \
  {                                                                            \
    const unsigned short* Ap_ = ((TT) >= 64) ? xl : xh;                        \
    const size_t ab_ = (size_t)(row0 + strow) * K_DIM + (((TT)&31) << 6) + stks; \
    char* d_ = smem + (((TT)&1) * 32768) + ldst;                               \
    _Pragma("unroll") for (int r_ = 0; r_ < 4; ++r_)                           \
        gload16(Ap_ + ab_ + (size_t)(r_ * 64) * K_DIM, d_ + r_ * 8192);        \
  }

#define STAGE_B(TT)                                                            \
  {                                                                            \
    const unsigned short* Bp_ = ((TT) >= 32 && (TT) < 64) ? wl : wh;           \
    const size_t bb_ = (size_t)(col0 + strow) * K_DIM + (((TT)&31) << 6) + stks; \
    char* d_ = smem + 65536 + (((TT)&1) * 32768) + ldst;                       \
    _Pragma("unroll") for (int r_ = 0; r_ < 4; ++r_)                           \
        gload16(Bp_ + bb_ + (size_t)(r_ * 64) * K_DIM, d_ + r_ * 8192);        \
  }

#define DS_A(MH)                                                               \
  _Pragma("unroll") for (int mi_ = 0; mi_ < 4; ++mi_)                          \
  _Pragma("unroll") for (int kh_ = 0; kh_ < 2; ++kh_)                          \
      af[mi_][kh_] = *reinterpret_cast<const bf16x8*>(                         \
          smem + aslot + abase + ((MH)*4 + mi_) * 2048 + kh_ * 512);

#define DS_B(NH)                                                               \
  _Pragma("unroll") for (int ni_ = 0; ni_ < 2; ++ni_)                          \
  _Pragma("unroll") for (int kh_ = 0; kh_ < 2; ++kh_)                          \
      bf[ni_][kh_] = *reinterpret_cast<const bf16x8*>(                         \
          smem + bslot + bbase + ((NH)*2 + ni_) * 2048 + kh_ * 512);

#define MFMA16(MH, NH)                                                         \
  __builtin_amdgcn_s_setprio(1);                                               \
  _Pragma("unroll") for (int kh_ = 0; kh_ < 2; ++kh_)                          \
  _Pragma("unroll") for (int mi_ = 0; mi_ < 4; ++mi_)                          \
  _Pragma("unroll") for (int ni_ = 0; ni_ < 2; ++ni_)                          \
      acc[(MH)*4 + mi_][(NH)*2 + ni_] = __builtin_amdgcn_mfma_f32_16x16x32_bf16( \
          af[mi_][kh_], bf[ni_][kh_], acc[(MH)*4 + mi_][(NH)*2 + ni_], 0, 0, 0); \
  __builtin_amdgcn_s_setprio(0);

#define BARRIER                                                                \
  {                                                                            \
    __builtin_amdgcn_s_barrier();                                              \
    __builtin_amdgcn_sched_barrier(0);                                         \
  }

__global__ __launch_bounds__(512, 2) void gemm8p_kernel(
    const unsigned short* __restrict__ xh, const unsigned short* __restrict__ xl,
    const unsigned short* __restrict__ wh, const unsigned short* __restrict__ wl,
    const float* __restrict__ xe_packed, const float* __restrict__ we_packed,
    const float* __restrict__ bias, const float* __restrict__ swp,
    const float* __restrict__ sbp, float* __restrict__ out) {
  __shared__ __align__(16) char smem[131072];

  int bid = blockIdx.x;
  int sid = (bid & 7) * 64 + (bid >> 3);   // XCD swizzle, 512 % 8 == 0 bijective
  int bm = sid >> 5, bn = sid & 31;
  int row0 = bm * 256, col0 = bn * 256;

  int tid = threadIdx.x;
  int lane = tid & 63, w = tid >> 6;
  int wave_m = w >> 2, wave_n = w & 3;
  int cl = lane & 15, g = lane >> 4;

  // frag base byte offsets within a panel
  int abase = (wave_m * 16 + (cl >> 3)) * 1024 + g * 128 + (cl & 7) * 16;
  int bbase = (wave_n * 8 + (cl >> 3)) * 1024 + g * 128 + (cl & 7) * 16;

  // staging per-thread source permutation
  int strow = (tid >> 6) * 8 + (tid & 7);  // row within 64-row round
  int stks = ((tid >> 3) & 7) * 8;         // k element offset
  int ldst = tid * 16;                     // linear LDS byte dest within round

  // ---- phase 0: exact-fp32 gate -> 128-bit register mask ----
  float* xe_l = (float*)smem;            // [256][36]
  float* we_l = (float*)(smem + 36864);  // [256][36]
#pragma unroll
  for (int it = 0; it < 4; ++it) {
    int idx = it * 512 + tid;
    int r = idx >> 3, q = (idx & 7) * 4;
    *reinterpret_cast<float4*>(xe_l + r * 36 + q) =
        *reinterpret_cast<const float4*>(xe_packed + (size_t)(row0 + r) * 32 + q);
    *reinterpret_cast<float4*>(we_l + r * 36 + q) =
        *reinterpret_cast<const float4*>(we_packed + (size_t)(col0 + r) * 32 + q);
  }
  __syncthreads();
  float sw = *swp, sb = *sbp;
  float bv[4];
#pragma unroll
  for (int n = 0; n < 4; ++n) bv[n] = bias[col0 + wave_n * 64 + n * 16 + cl];

  unsigned int umask[4] = {0u, 0u, 0u, 0u};
  {
    f32x4 wev[4][8];
#pragma unroll
    for (int n = 0; n < 4; ++n) {
      int colw = wave_n * 64 + n * 16 + cl;
#pragma unroll
      for (int kq = 0; kq < 8; ++kq)
        wev[n][kq] = *reinterpret_cast<const f32x4*>(we_l + colw * 36 + kq * 4);
    }
#pragma unroll
    for (int m = 0; m < 8; ++m) {
#pragma unroll
      for (int j = 0; j < 4; ++j) {
        int rl = wave_m * 128 + m * 16 + g * 4 + j;
        f32x4 xev[8], xev2[8];
#pragma unroll
        for (int kq = 0; kq < 8; ++kq) {
          xev[kq] = *reinterpret_cast<const f32x4*>(xe_l + rl * 36 + kq * 4);
          xev2[kq] = xev[kq] * xev[kq];
        }
#pragma unroll
        for (int n = 0; n < 4; ++n) {
          float y1 = 0.0f, sqv = 0.0f;
#pragma unroll
          for (int kq = 0; kq < 8; ++kq)
#pragma unroll
            for (int kk = 0; kk < 4; ++kk) {
              float wv = wev[n][kq][kk];
              y1 = fmaf(xev[kq][kk], wv, y1);
              sqv = fmaf(xev2[kq][kk], wv * wv, sqv);
            }
          if (gate_passed(y1 + bv[n], sqv, sw, sb))
            umask[m >> 1] |= 1u << ((m & 1) * 16 + n * 4 + j);
        }
      }
    }
  }
  __syncthreads();  // gate LDS region dead; GEMM staging may now overwrite

  f32x4 acc[8][4];
#pragma unroll
  for (int m = 0; m < 8; ++m)
#pragma unroll
    for (int n = 0; n < 4; ++n) acc[m][n] = (f32x4){0.f, 0.f, 0.f, 0.f};

  // ---- pipeline prologue: A[0], B[0], A[1] (12 loads/thread) ----
  STAGE_A(0);
  STAGE_B(0);
  STAGE_A(1);
  asm volatile("s_waitcnt vmcnt(4)" ::: "memory");  // A0,B0 landed; A1 in flight
  BARRIER;

  bf16x8 af[4][2];
  bf16x8 bf[2][2];

#pragma unroll 1
  for (int t = 0; t < NT; ++t) {
    int aslot = (t & 1) * 32768;
    int bslot = 65536 + (t & 1) * 32768;
    // q0: quadrant (0,0) — new A + new B frags; stage B[t+1]
    DS_A(0);
    DS_B(0);
    if (t + 1 < NT) STAGE_B(t + 1);
    BARRIER;
    MFMA16(0, 0);
    BARRIER;
    // q1: quadrant (0,1) — new B frags only
    DS_B(1);
    BARRIER;
    MFMA16(0, 1);
    BARRIER;
    // q2: quadrant (1,1) — new A frags only
    DS_A(1);
    BARRIER;
    MFMA16(1, 1);
    BARRIER;
    // q3: quadrant (1,0) — re-read B(0); stage A[t+2] (A slot last read in q2)
    DS_B(0);
    if (t + 2 < NT) STAGE_A(t + 2);
    BARRIER;
    MFMA16(1, 0);
    if (t <= NT - 3) {
      asm volatile("s_waitcnt vmcnt(4)" ::: "memory");  // drains A[t+1], B[t+1]
    } else if (t == NT - 2) {
      asm volatile("s_waitcnt vmcnt(0)" ::: "memory");  // tail drain
    }
    BARRIER;
  }

  // ---- epilogue: single fused masked store (C/D layout: col=lane&15, row=(lane>>4)*4+j) ----
#pragma unroll
  for (int m = 0; m < 8; ++m) {
    int rb = row0 + wave_m * 128 + m * 16 + g * 4;
#pragma unroll
    for (int n = 0; n < 4; ++n) {
      int c = col0 + wave_n * 64 + n * 16 + cl;
#pragma unroll
      for (int j = 0; j < 4; ++j) {
        unsigned int bit = (umask[m >> 1] >> ((m & 1) * 16 + n * 4 + j)) & 1u;
        out[(size_t)(rb + j) * N_DIM + c] = bit ? 0.0f : (acc[m][n][j] + bv[n]);
      }
    }
  }
}

// ---------------- fp32 fallback (only if ws_size too small) ----------------
__device__ __forceinline__ void stats4x4(const float* __restrict__ x,
                                         const float* __restrict__ w,
                                         int r0, int c0,
                                         float (&y1)[4][4], float (&sq)[4][4]) {
#pragma unroll
  for (int i = 0; i < 4; ++i)
#pragma unroll
    for (int j = 0; j < 4; ++j) { y1[i][j] = 0.0f; sq[i][j] = 0.0f; }
#pragma unroll
  for (int kc = 0; kc < 8; ++kc) {
    float4 xa[4], wa[4], x2[4], w2[4];
#pragma unroll
    for (int i = 0; i < 4; ++i)
      xa[i] = *reinterpret_cast<const float4*>(x + (size_t)(r0 + i) * K_DIM + kc * 4);
#pragma unroll
    for (int j = 0; j < 4; ++j)
      wa[j] = *reinterpret_cast<const float4*>(w + (size_t)(c0 + j) * K_DIM + kc * 4);
#pragma unroll
    for (int i = 0; i < 4; ++i)
      x2[i] = make_float4(xa[i].x * xa[i].x, xa[i].y * xa[i].y,
                          xa[i].z * xa[i].z, xa[i].w * xa[i].w);
#pragma unroll
    for (int j = 0; j < 4; ++j)
      w2[j] = make_float4(wa[j].x * wa[j].x, wa[j].y * wa[j].y,
                          wa[j].z * wa[j].z, wa[j].w * wa[j].w);
#pragma unroll
    for (int i = 0; i < 4; ++i)
#pragma unroll
      for (int j = 0; j < 4; ++j) {
        float a = y1[i][j];
        a = fmaf(xa[i].x, wa[j].x, a);
        a = fmaf(xa[i].y, wa[j].y, a);
        a = fmaf(xa[i].z, wa[j].z, a);
        a = fmaf(xa[i].w, wa[j].w, a);
        y1[i][j] = a;
        float b = sq[i][j];
        b = fmaf(x2[i].x, w2[j].x, b);
        b = fmaf(x2[i].y, w2[j].y, b);
        b = fmaf(x2[i].z, w2[j].z, b);
        b = fmaf(x2[i].w, w2[j].w, b);
        sq[i][j] = b;
      }
  }
}

__global__ void fallback_gemm_kernel(const float* __restrict__ x, const float* __restrict__ wgt,
                                     const float* __restrict__ bias, const float* __restrict__ swp,
                                     const float* __restrict__ sbp, float* __restrict__ out) {
  __shared__ float xs[64][36], ws2[64][36];
  int t = threadIdx.x;
  int tr = t >> 4, tc = t & 15;
  int r0 = blockIdx.x * 64, c0 = blockIdx.y * 64;
  float acc[4][4];
#pragma unroll
  for (int i = 0; i < 4; ++i)
#pragma unroll
    for (int j = 0; j < 4; ++j) acc[i][j] = 0.0f;

#pragma unroll 1
  for (int kt = 0; kt < K_DIM / 32; ++kt) {
#pragma unroll
    for (int i = 0; i < 2; ++i) {
      int idx = t + 256 * i;
      int row = idx >> 3;
      int kk = (idx & 7) * 4;
      *reinterpret_cast<float4*>(&xs[row][kk]) =
          *reinterpret_cast<const float4*>(x + (size_t)(r0 + row) * K_DIM + kt * 32 + kk);
      *reinterpret_cast<float4*>(&ws2[row][kk]) =
          *reinterpret_cast<const float4*>(wgt + (size_t)(c0 + row) * K_DIM + kt * 32 + kk);
    }
    __syncthreads();
#pragma unroll 4
    for (int k = 0; k < 32; ++k) {
      float xv[4], wv[4];
#pragma unroll
      for (int i = 0; i < 4; ++i) { xv[i] = xs[tr * 4 + i][k]; wv[i] = ws2[tc * 4 + i][k]; }
#pragma unroll
      for (int i = 0; i < 4; ++i)
#pragma unroll
        for (int j = 0; j < 4; ++j) acc[i][j] = fmaf(xv[i], wv[j], acc[i][j]);
    }
    __syncthreads();
  }

  float y1[4][4], sq[4][4];
  stats4x4(x, wgt, r0 + tr * 4, c0 + tc * 4, y1, sq);
  float sw = *swp, sb = *sbp;
#pragma unroll
  for (int i = 0; i < 4; ++i)
#pragma unroll
    for (int j = 0; j < 4; ++j) {
      int r = r0 + tr * 4 + i, c = c0 + tc * 4 + j;
      float bvv = bias[c];
      unsigned char p = gate_passed(y1[i][j] + bvv, sq[i][j], sw, sb);
      out[(size_t)r * N_DIM + c] = p ? 0.0f : (acc[i][j] + bvv);
    }
}

extern "C" void kernel_launch(void* const* d_in, const int* in_sizes, int n_in,
                              void* d_out, int out_size, void* d_ws, size_t ws_size,
                              hipStream_t stream) {
  (void)in_sizes; (void)n_in; (void)out_size;
  const float* x    = (const float*)d_in[0];
  const float* wgt  = (const float*)d_in[1];
  const float* bias = (const float*)d_in[2];
  const float* swp  = (const float*)d_in[3];
  const float* sbp  = (const float*)d_in[4];
  float* out = (float*)d_out;

  const size_t xh_off = 0;
  const size_t xl_off = xh_off + (size_t)M_DIM * K_DIM * 2;    // 16 MB
  const size_t wh_off = xl_off + (size_t)M_DIM * K_DIM * 2;    // 32 MB
  const size_t wl_off = wh_off + (size_t)N_DIM * K_DIM * 2;    // 64 MB
  const size_t xe_off = wl_off + (size_t)N_DIM * K_DIM * 2;    // 96 MB
  const size_t we_off = xe_off + (size_t)M_DIM * 32 * 4;       // +512 KB
  const size_t need   = we_off + (size_t)N_DIM * 32 * 4;       // +1 MB

  if (ws_size >= need) {
    unsigned short* xh = (unsigned short*)((char*)d_ws + xh_off);
    unsigned short* xl = (unsigned short*)((char*)d_ws + xl_off);
    unsigned short* wh = (unsigned short*)((char*)d_ws + wh_off);
    unsigned short* wl = (unsigned short*)((char*)d_ws + wl_off);
    float* xe = (float*)((char*)d_ws + xe_off);
    float* we = (float*)((char*)d_ws + we_off);

    hipLaunchKernelGGL(split_bf16_kernel, dim3(2048), dim3(256), 0, stream,
                       x, xh, xl, xe, M_DIM * K_DIM / 4);
    hipLaunchKernelGGL(split_bf16_kernel, dim3(2048), dim3(256), 0, stream,
                       wgt, wh, wl, we, N_DIM * K_DIM / 4);
    hipLaunchKernelGGL(gemm8p_kernel, dim3(512), dim3(512), 0, stream,
                       xh, xl, wh, wl, xe, we, bias, swp, sbp, out);
  } else {
    hipLaunchKernelGGL(fallback_gemm_kernel, dim3(M_DIM / 64, N_DIM / 64), dim3(256), 0, stream,
                       x, wgt, bias, swp, sbp, out);
  }
}

// Round 6
// 295.633 us; speedup vs baseline: 3.8901x; 3.8901x over previous
//
#include <hip/hip_runtime.h>
#include <hip/hip_bf16.h>
#include <hip/hip_fp16.h>
#include <stdint.h>

#define M_DIM 4096   // B*S
#define K_DIM 2048   // H
#define N_DIM 8192   // OUT

typedef __attribute__((ext_vector_type(4))) float f32x4;
typedef __attribute__((ext_vector_type(8))) _Float16 f16x8;

typedef __attribute__((address_space(1))) const unsigned int g_u32_t;
typedef __attribute__((address_space(3))) unsigned int lds_u32_t;

static __device__ __forceinline__ void gload16(const void* g, void* l) {
  // global -> LDS direct copy, 16B per lane; LDS dest = wave-uniform base + lane*16
  __builtin_amdgcn_global_load_lds((g_u32_t*)g, (lds_u32_t*)l, 16, 0, 0);
}

#define BOUNDF ((float)(-2.053748910631823))

__device__ __forceinline__ unsigned char gate_passed(float y1v, float sqv,
                                                     float sw, float sb) {
  // exactly mirrors the reference formula order (sw=1, sb=0 at runtime)
  float cm = y1v / 32.0f * sw + sb;
  float cv = (sqv / 32.0f - cm * cm) * sw * sw;
  float ts = cm / sqrtf(cv / 32.0f);
  return (ts < BOUNDF) ? (unsigned char)1 : (unsigned char)0;
}

// ---------------- convert fp32 -> fp16 (RTN), plus packed E-prefix copy ----------------
// packed_e gets the first 32 fp32 of each K_DIM-length row, contiguous: [rows][32].
__global__ void cvt_f16_kernel(const float* __restrict__ src,
                               unsigned short* __restrict__ dst,
                               float* __restrict__ packed_e,
                               int n4) {
  int i = blockIdx.x * blockDim.x + threadIdx.x;
  int stride = gridDim.x * blockDim.x;
  for (; i < n4; i += stride) {
    float4 v = reinterpret_cast<const float4*>(src)[i];
    int col4 = i & (K_DIM / 4 - 1);
    if (col4 < 8) {
      int row = i >> 9;  // K_DIM/4 = 512
      reinterpret_cast<float4*>(packed_e)[row * 8 + col4] = v;
    }
    float xs[4] = {v.x, v.y, v.z, v.w};
    unsigned short hb[4];
#pragma unroll
    for (int j = 0; j < 4; ++j) {
      _Float16 h = (_Float16)xs[j];  // v_cvt_f16_f32, round-to-nearest
      hb[j] = *reinterpret_cast<unsigned short*>(&h);
    }
    reinterpret_cast<ushort4*>(dst)[i] = make_ushort4(hb[0], hb[1], hb[2], hb[3]);
  }
}

// ---------------- main GEMM: single fp16 MFMA term + fused exact-fp32 gate ----------------
// m97 structure: 128x128 tile, BK=32, 4 waves, global_load_lds width 16,
// XOR-swizzled 16B LDS slots, 8 ds_read_b128 + 16 MFMA per K-step.
__global__ __launch_bounds__(256, 2) void gemm_f16_kernel(
    const unsigned short* __restrict__ xf, const unsigned short* __restrict__ wf,
    const float* __restrict__ xe_packed, const float* __restrict__ we_packed,
    const float* __restrict__ bias, const float* __restrict__ swp,
    const float* __restrict__ sbp, float* __restrict__ out) {
  // K-loop phase: A | B, each 128 rows x 32 k f16 (8 KB), XOR-swizzled 16B slots.
  // Epilogue phase (reuses same LDS): xe_lds [128][36] f32 + we_lds [32][128] f32.
  __shared__ __align__(16) unsigned char smem_bytes[128 * 36 * 4 + 32 * 128 * 4];
  unsigned short* smem = (unsigned short*)smem_bytes;

  // XCD-aware swizzle (2048 blocks % 8 == 0 -> simple remap is bijective)
  int bid = blockIdx.x;
  int sid = (bid & 7) * 256 + (bid >> 3);
  int bm = sid >> 6;   // 0..31
  int bn = sid & 63;   // 0..63
  int row0 = bm * 128, col0 = bn * 128;

  int t = threadIdx.x, lane = t & 63, w = t >> 6;
  int wrow = (w >> 1) * 64, wcol = (w & 1) * 64;

  // staging geometry: linear LDS byte L = (w*2+i)*1024 + lane*16
  // row = L>>6 (64B rows), slot s = (L>>4)&3; slot s holds global k-group g = s ^ ((row>>1)&3)
  int Lr[2], Lg[2];
#pragma unroll
  for (int i = 0; i < 2; ++i) {
    int L = (w * 2 + i) * 1024 + lane * 16;
    int row = L >> 6;
    int s = (L >> 4) & 3;
    Lr[i] = row;
    Lg[i] = s ^ ((row >> 1) & 3);
  }

  // fragment read offsets (halfwords), constant over kt
  // A-frag (16x16x32): row = lane&15, k-group = lane>>4 (8 consecutive k)
  int aoff[4], boff[4];
  int g = lane >> 4;
#pragma unroll
  for (int m = 0; m < 4; ++m) {
    int row = wrow + m * 16 + (lane & 15);
    aoff[m] = row * 32 + ((g ^ ((row >> 1) & 3)) * 8);
  }
#pragma unroll
  for (int n = 0; n < 4; ++n) {
    int row = wcol + n * 16 + (lane & 15);
    boff[n] = row * 32 + ((g ^ ((row >> 1) & 3)) * 8);
  }

  f32x4 acc[4][4];
#pragma unroll
  for (int m = 0; m < 4; ++m)
#pragma unroll
    for (int n = 0; n < 4; ++n) acc[m][n] = (f32x4){0.0f, 0.0f, 0.0f, 0.0f};

  const unsigned short* srcs[2] = {xf, wf};
  int rbase[2] = {row0, col0};

#pragma unroll 1
  for (int kt = 0; kt < K_DIM / 32; ++kt) {
    int k0 = kt * 32;
    // stage 2 panels (2 issues per wave per panel); global src pre-inverse-swizzled
#pragma unroll
    for (int tt = 0; tt < 2; ++tt) {
#pragma unroll
      for (int i = 0; i < 2; ++i) {
        const unsigned short* gp =
            srcs[tt] + (size_t)(rbase[tt] + Lr[i]) * K_DIM + (k0 + Lg[i] * 8);
        char* lp = (char*)smem + tt * 8192 + (w * 2 + i) * 1024;
        gload16(gp, lp);
      }
    }
    __syncthreads();  // compiler drains vmcnt(0) before barrier -> panels ready

    f16x8 a[4], b[4];
#pragma unroll
    for (int m = 0; m < 4; ++m)
      a[m] = *reinterpret_cast<const f16x8*>(&smem[0 * 4096 + aoff[m]]);
#pragma unroll
    for (int n = 0; n < 4; ++n)
      b[n] = *reinterpret_cast<const f16x8*>(&smem[1 * 4096 + boff[n]]);
#pragma unroll
    for (int m = 0; m < 4; ++m)
#pragma unroll
      for (int n = 0; n < 4; ++n)
        acc[m][n] = __builtin_amdgcn_mfma_f32_16x16x32_f16(a[m], b[n], acc[m][n], 0, 0, 0);
    __syncthreads();
  }

  // ---- fused gate epilogue: exact fp32 E=32 stats from packed prefixes ----
  float* xe_lds = (float*)smem_bytes;                        // [128][36] padded
  float* we_lds = (float*)(smem_bytes + 128 * 36 * 4);       // [32][128] k-major

  // stage x_e tile: 128 rows x 32 f32 = 1024 float4; 4 per thread
#pragma unroll
  for (int it = 0; it < 4; ++it) {
    int idx = it * 256 + t;
    int r = idx >> 3, q = idx & 7;
    float4 v = reinterpret_cast<const float4*>(xe_packed)[(size_t)(row0 + r) * 8 + q];
    *reinterpret_cast<float4*>(&xe_lds[r * 36 + q * 4]) = v;
  }
  // stage w_e tile transposed to k-major: [32][128]
#pragma unroll
  for (int it = 0; it < 4; ++it) {
    int idx = it * 256 + t;
    int c = idx & 127, kq = idx >> 7;  // kq = 0..7
    float4 v = reinterpret_cast<const float4*>(we_packed)[(size_t)(col0 + c) * 8 + kq];
    we_lds[(kq * 4 + 0) * 128 + c] = v.x;
    we_lds[(kq * 4 + 1) * 128 + c] = v.y;
    we_lds[(kq * 4 + 2) * 128 + c] = v.z;
    we_lds[(kq * 4 + 3) * 128 + c] = v.w;
  }
  __syncthreads();

  float sw = *swp, sb = *sbp;
  int cl = lane & 15, rg = lane >> 4;

  // Fully unrolled (rule #20: every acc index compile-time constant).
#pragma unroll
  for (int m = 0; m < 4; ++m) {
    float y1[4][4], sq[4][4];  // [j][n]
#pragma unroll
    for (int j = 0; j < 4; ++j)
#pragma unroll
      for (int n = 0; n < 4; ++n) { y1[j][n] = 0.0f; sq[j][n] = 0.0f; }
    int rb0 = wrow + m * 16 + rg * 4;  // local row base in tile
#pragma unroll 4
    for (int k = 0; k < 32; ++k) {
      float wv[4], wv2[4];
#pragma unroll
      for (int n = 0; n < 4; ++n) {
        wv[n] = we_lds[k * 128 + wcol + n * 16 + cl];
        wv2[n] = wv[n] * wv[n];
      }
#pragma unroll
      for (int j = 0; j < 4; ++j) {
        float xv = xe_lds[(rb0 + j) * 36 + k];
        float xv2 = xv * xv;
#pragma unroll
        for (int n = 0; n < 4; ++n) {
          y1[j][n] = fmaf(xv, wv[n], y1[j][n]);
          sq[j][n] = fmaf(xv2, wv2[n], sq[j][n]);
        }
      }
    }
    // apply gate + store  (C/D layout: col = lane&15, row = (lane>>4)*4 + j  [m89])
#pragma unroll
    for (int n = 0; n < 4; ++n) {
      int c = col0 + wcol + n * 16 + cl;
      float bv = bias[c];
#pragma unroll
      for (int j = 0; j < 4; ++j) {
        float v = acc[m][n][j] + bv;
        float y1v = y1[j][n] + bv;
        unsigned char p = gate_passed(y1v, sq[j][n], sw, sb);
        int r = row0 + wrow + m * 16 + rg * 4 + j;
        out[(size_t)r * N_DIM + c] = p ? 0.0f : v;
      }
    }
  }
}

// ---------------- fp32 fallback (only if ws_size too small) ----------------
__device__ __forceinline__ void stats4x4(const float* __restrict__ x,
                                         const float* __restrict__ w,
                                         int r0, int c0,
                                         float (&y1)[4][4], float (&sq)[4][4]) {
#pragma unroll
  for (int i = 0; i < 4; ++i)
#pragma unroll
    for (int j = 0; j < 4; ++j) { y1[i][j] = 0.0f; sq[i][j] = 0.0f; }
#pragma unroll
  for (int kc = 0; kc < 8; ++kc) {
    float4 xa[4], wa[4], x2[4], w2[4];
#pragma unroll
    for (int i = 0; i < 4; ++i)
      xa[i] = *reinterpret_cast<const float4*>(x + (size_t)(r0 + i) * K_DIM + kc * 4);
#pragma unroll
    for (int j = 0; j < 4; ++j)
      wa[j] = *reinterpret_cast<const float4*>(w + (size_t)(c0 + j) * K_DIM + kc * 4);
#pragma unroll
    for (int i = 0; i < 4; ++i)
      x2[i] = make_float4(xa[i].x * xa[i].x, xa[i].y * xa[i].y,
                          xa[i].z * xa[i].z, xa[i].w * xa[i].w);
#pragma unroll
    for (int j = 0; j < 4; ++j)
      w2[j] = make_float4(wa[j].x * wa[j].x, wa[j].y * wa[j].y,
                          wa[j].z * wa[j].z, wa[j].w * wa[j].w);
#pragma unroll
    for (int i = 0; i < 4; ++i)
#pragma unroll
      for (int j = 0; j < 4; ++j) {
        float a = y1[i][j];
        a = fmaf(xa[i].x, wa[j].x, a);
        a = fmaf(xa[i].y, wa[j].y, a);
        a = fmaf(xa[i].z, wa[j].z, a);
        a = fmaf(xa[i].w, wa[j].w, a);
        y1[i][j] = a;
        float b = sq[i][j];
        b = fmaf(x2[i].x, w2[j].x, b);
        b = fmaf(x2[i].y, w2[j].y, b);
        b = fmaf(x2[i].z, w2[j].z, b);
        b = fmaf(x2[i].w, w2[j].w, b);
        sq[i][j] = b;
      }
  }
}

__global__ void fallback_gemm_kernel(const float* __restrict__ x, const float* __restrict__ wgt,
                                     const float* __restrict__ bias, const float* __restrict__ swp,
                                     const float* __restrict__ sbp, float* __restrict__ out) {
  __shared__ float xs[64][36], ws2[64][36];
  int t = threadIdx.x;
  int tr = t >> 4, tc = t & 15;
  int r0 = blockIdx.x * 64, c0 = blockIdx.y * 64;
  float acc[4][4];
#pragma unroll
  for (int i = 0; i < 4; ++i)
#pragma unroll
    for (int j = 0; j < 4; ++j) acc[i][j] = 0.0f;

#pragma unroll 1
  for (int kt = 0; kt < K_DIM / 32; ++kt) {
#pragma unroll
    for (int i = 0; i < 2; ++i) {
      int idx = t + 256 * i;
      int row = idx >> 3;
      int kk = (idx & 7) * 4;
      *reinterpret_cast<float4*>(&xs[row][kk]) =
          *reinterpret_cast<const float4*>(x + (size_t)(r0 + row) * K_DIM + kt * 32 + kk);
      *reinterpret_cast<float4*>(&ws2[row][kk]) =
          *reinterpret_cast<const float4*>(wgt + (size_t)(c0 + row) * K_DIM + kt * 32 + kk);
    }
    __syncthreads();
#pragma unroll 4
    for (int k = 0; k < 32; ++k) {
      float xv[4], wv[4];
#pragma unroll
      for (int i = 0; i < 4; ++i) { xv[i] = xs[tr * 4 + i][k]; wv[i] = ws2[tc * 4 + i][k]; }
#pragma unroll
      for (int i = 0; i < 4; ++i)
#pragma unroll
        for (int j = 0; j < 4; ++j) acc[i][j] = fmaf(xv[i], wv[j], acc[i][j]);
    }
    __syncthreads();
  }

  float y1[4][4], sq[4][4];
  stats4x4(x, wgt, r0 + tr * 4, c0 + tc * 4, y1, sq);
  float sw = *swp, sb = *sbp;
#pragma unroll
  for (int i = 0; i < 4; ++i)
#pragma unroll
    for (int j = 0; j < 4; ++j) {
      int r = r0 + tr * 4 + i, c = c0 + tc * 4 + j;
      float bv = bias[c];
      unsigned char p = gate_passed(y1[i][j] + bv, sq[i][j], sw, sb);
      out[(size_t)r * N_DIM + c] = p ? 0.0f : (acc[i][j] + bv);
    }
}

extern "C" void kernel_launch(void* const* d_in, const int* in_sizes, int n_in,
                              void* d_out, int out_size, void* d_ws, size_t ws_size,
                              hipStream_t stream) {
  (void)in_sizes; (void)n_in; (void)out_size;
  const float* x    = (const float*)d_in[0];
  const float* wgt  = (const float*)d_in[1];
  const float* bias = (const float*)d_in[2];
  const float* swp  = (const float*)d_in[3];
  const float* sbp  = (const float*)d_in[4];
  float* out = (float*)d_out;

  const size_t xf_off = 0;
  const size_t wf_off = xf_off + (size_t)M_DIM * K_DIM * 2;    // 16 MB
  const size_t xe_off = wf_off + (size_t)N_DIM * K_DIM * 2;    // 48 MB
  const size_t we_off = xe_off + (size_t)M_DIM * 32 * 4;       // +512 KB
  const size_t need   = we_off + (size_t)N_DIM * 32 * 4;       // +1 MB

  if (ws_size >= need) {
    unsigned short* xf = (unsigned short*)((char*)d_ws + xf_off);
    unsigned short* wf = (unsigned short*)((char*)d_ws + wf_off);
    float* xe = (float*)((char*)d_ws + xe_off);
    float* we = (float*)((char*)d_ws + we_off);

    hipLaunchKernelGGL(cvt_f16_kernel, dim3(2048), dim3(256), 0, stream,
                       x, xf, xe, M_DIM * K_DIM / 4);
    hipLaunchKernelGGL(cvt_f16_kernel, dim3(2048), dim3(256), 0, stream,
                       wgt, wf, we, N_DIM * K_DIM / 4);
    hipLaunchKernelGGL(gemm_f16_kernel, dim3(2048), dim3(256), 0, stream,
                       xf, wf, xe, we, bias, swp, sbp, out);
  } else {
    hipLaunchKernelGGL(fallback_gemm_kernel, dim3(M_DIM / 64, N_DIM / 64), dim3(256), 0, stream,
                       x, wgt, bias, swp, sbp, out);
  }
}

// Round 7
// 292.418 us; speedup vs baseline: 3.9328x; 1.0110x over previous
//
#include <hip/hip_runtime.h>
#include <hip/hip_bf16.h>
#include <hip/hip_fp16.h>
#include <stdint.h>

#define M_DIM 4096   // B*S
#define K_DIM 2048   // H
#define N_DIM 8192   // OUT

typedef __attribute__((ext_vector_type(4))) float f32x4;
typedef __attribute__((ext_vector_type(8))) _Float16 f16x8;

typedef __attribute__((address_space(1))) const unsigned int g_u32_t;
typedef __attribute__((address_space(3))) unsigned int lds_u32_t;

static __device__ __forceinline__ void gload16(const void* g, void* l) {
  // global -> LDS direct copy, 16B per lane; LDS dest = wave-uniform base + lane*16
  __builtin_amdgcn_global_load_lds((g_u32_t*)g, (lds_u32_t*)l, 16, 0, 0);
}

#define BOUNDF ((float)(-2.053748910631823))

__device__ __forceinline__ unsigned char gate_passed(float y1v, float sqv,
                                                     float sw, float sb) {
  // exactly mirrors the reference formula order (sw=1, sb=0 at runtime)
  float cm = y1v / 32.0f * sw + sb;
  float cv = (sqv / 32.0f - cm * cm) * sw * sw;
  float ts = cm / sqrtf(cv / 32.0f);
  return (ts < BOUNDF) ? (unsigned char)1 : (unsigned char)0;
}

// ------- fused convert fp32 -> fp16 (RTN) for BOTH x and w, plus packed E-prefix -------
__global__ void cvt_f16_fused_kernel(const float* __restrict__ x,
                                     const float* __restrict__ wgt,
                                     unsigned short* __restrict__ xf,
                                     unsigned short* __restrict__ wf,
                                     float* __restrict__ xe,
                                     float* __restrict__ we,
                                     int n4x, int n4tot) {
  int i = blockIdx.x * blockDim.x + threadIdx.x;
  int stride = gridDim.x * blockDim.x;
  for (; i < n4tot; i += stride) {
    const float* src;
    unsigned short* dst;
    float* pe;
    int idx;
    if (i < n4x) {
      src = x; dst = xf; pe = xe; idx = i;
    } else {
      src = wgt; dst = wf; pe = we; idx = i - n4x;
    }
    float4 v = reinterpret_cast<const float4*>(src)[idx];
    int col4 = idx & (K_DIM / 4 - 1);
    if (col4 < 8) {
      int row = idx >> 9;  // K_DIM/4 = 512
      reinterpret_cast<float4*>(pe)[row * 8 + col4] = v;
    }
    float xs[4] = {v.x, v.y, v.z, v.w};
    unsigned short hb[4];
#pragma unroll
    for (int j = 0; j < 4; ++j) {
      _Float16 h = (_Float16)xs[j];  // v_cvt_f16_f32, round-to-nearest
      hb[j] = *reinterpret_cast<unsigned short*>(&h);
    }
    reinterpret_cast<ushort4*>(dst)[idx] = make_ushort4(hb[0], hb[1], hb[2], hb[3]);
  }
}

// ---------------- main GEMM: single fp16 MFMA term + fused exact-fp32 gate ----------------
// m97 structure: 128x128 tile, BK=32, 4 waves, global_load_lds width 16,
// XOR-swizzled 16B LDS slots, 8 ds_read_b128 + 16 MFMA per K-step.
// LDS = exactly 32 KB -> 5 blocks/CU residency.
__global__ __launch_bounds__(256, 2) void gemm_f16_kernel(
    const unsigned short* __restrict__ xf, const unsigned short* __restrict__ wf,
    const float* __restrict__ xe_packed, const float* __restrict__ we_packed,
    const float* __restrict__ bias, const float* __restrict__ swp,
    const float* __restrict__ sbp, float* __restrict__ out) {
  // K-loop phase: A | B, each 128 rows x 32 k f16 (8 KB), XOR-swizzled 16B slots.
  // Epilogue phase (reuses same LDS): xe_lds [128][32] f32 (broadcast reads -> no
  // padding needed) + we_lds [32][128] f32. Total 32768 B.
  __shared__ __align__(16) unsigned char smem_bytes[128 * 32 * 4 + 32 * 128 * 4];
  unsigned short* smem = (unsigned short*)smem_bytes;

  // XCD-aware swizzle (2048 blocks % 8 == 0 -> simple remap is bijective)
  int bid = blockIdx.x;
  int sid = (bid & 7) * 256 + (bid >> 3);
  int bm = sid >> 6;   // 0..31
  int bn = sid & 63;   // 0..63
  int row0 = bm * 128, col0 = bn * 128;

  int t = threadIdx.x, lane = t & 63, w = t >> 6;
  int wrow = (w >> 1) * 64, wcol = (w & 1) * 64;

  // staging geometry: linear LDS byte L = (w*2+i)*1024 + lane*16
  // row = L>>6 (64B rows), slot s = (L>>4)&3; slot s holds global k-group g = s ^ ((row>>1)&3)
  int Lr[2], Lg[2];
#pragma unroll
  for (int i = 0; i < 2; ++i) {
    int L = (w * 2 + i) * 1024 + lane * 16;
    int row = L >> 6;
    int s = (L >> 4) & 3;
    Lr[i] = row;
    Lg[i] = s ^ ((row >> 1) & 3);
  }

  // fragment read offsets (halfwords), constant over kt
  int aoff[4], boff[4];
  int g = lane >> 4;
#pragma unroll
  for (int m = 0; m < 4; ++m) {
    int row = wrow + m * 16 + (lane & 15);
    aoff[m] = row * 32 + ((g ^ ((row >> 1) & 3)) * 8);
  }
#pragma unroll
  for (int n = 0; n < 4; ++n) {
    int row = wcol + n * 16 + (lane & 15);
    boff[n] = row * 32 + ((g ^ ((row >> 1) & 3)) * 8);
  }

  f32x4 acc[4][4];
#pragma unroll
  for (int m = 0; m < 4; ++m)
#pragma unroll
    for (int n = 0; n < 4; ++n) acc[m][n] = (f32x4){0.0f, 0.0f, 0.0f, 0.0f};

  // running staging pointers (strength-reduced: +32 halfwords per K-step)
  const unsigned short* gpa0 = xf + (size_t)(row0 + Lr[0]) * K_DIM + Lg[0] * 8;
  const unsigned short* gpa1 = xf + (size_t)(row0 + Lr[1]) * K_DIM + Lg[1] * 8;
  const unsigned short* gpb0 = wf + (size_t)(col0 + Lr[0]) * K_DIM + Lg[0] * 8;
  const unsigned short* gpb1 = wf + (size_t)(col0 + Lr[1]) * K_DIM + Lg[1] * 8;
  char* lpa0 = (char*)smem + (w * 2 + 0) * 1024;
  char* lpa1 = (char*)smem + (w * 2 + 1) * 1024;
  char* lpb0 = lpa0 + 8192;
  char* lpb1 = lpa1 + 8192;

#pragma unroll 1
  for (int kt = 0; kt < K_DIM / 32; ++kt) {
    gload16(gpa0, lpa0);
    gload16(gpa1, lpa1);
    gload16(gpb0, lpb0);
    gload16(gpb1, lpb1);
    gpa0 += 32; gpa1 += 32; gpb0 += 32; gpb1 += 32;
    __syncthreads();  // compiler drains vmcnt(0) before barrier -> panels ready

    f16x8 a[4], b[4];
#pragma unroll
    for (int m = 0; m < 4; ++m)
      a[m] = *reinterpret_cast<const f16x8*>(&smem[0 * 4096 + aoff[m]]);
#pragma unroll
    for (int n = 0; n < 4; ++n)
      b[n] = *reinterpret_cast<const f16x8*>(&smem[1 * 4096 + boff[n]]);
#pragma unroll
    for (int m = 0; m < 4; ++m)
#pragma unroll
      for (int n = 0; n < 4; ++n)
        acc[m][n] = __builtin_amdgcn_mfma_f32_16x16x32_f16(a[m], b[n], acc[m][n], 0, 0, 0);
    __syncthreads();
  }

  // ---- fused gate epilogue: exact fp32 E=32 stats from packed prefixes ----
  float* xe_lds = (float*)smem_bytes;                        // [128][32] (broadcast reads)
  float* we_lds = (float*)(smem_bytes + 128 * 32 * 4);       // [32][128] k-major

  // stage x_e tile: 128 rows x 32 f32 = 1024 float4; 4 per thread
#pragma unroll
  for (int it = 0; it < 4; ++it) {
    int idx = it * 256 + t;
    int r = idx >> 3, q = idx & 7;
    float4 v = reinterpret_cast<const float4*>(xe_packed)[(size_t)(row0 + r) * 8 + q];
    *reinterpret_cast<float4*>(&xe_lds[r * 32 + q * 4]) = v;
  }
  // stage w_e tile transposed to k-major: [32][128]
#pragma unroll
  for (int it = 0; it < 4; ++it) {
    int idx = it * 256 + t;
    int c = idx & 127, kq = idx >> 7;  // kq = 0..7
    float4 v = reinterpret_cast<const float4*>(we_packed)[(size_t)(col0 + c) * 8 + kq];
    we_lds[(kq * 4 + 0) * 128 + c] = v.x;
    we_lds[(kq * 4 + 1) * 128 + c] = v.y;
    we_lds[(kq * 4 + 2) * 128 + c] = v.z;
    we_lds[(kq * 4 + 3) * 128 + c] = v.w;
  }
  __syncthreads();

  float sw = *swp, sb = *sbp;
  int cl = lane & 15, rg = lane >> 4;

  // Fully unrolled (rule #20: every acc index compile-time constant).
#pragma unroll
  for (int m = 0; m < 4; ++m) {
    float y1[4][4], sq[4][4];  // [j][n]
#pragma unroll
    for (int j = 0; j < 4; ++j)
#pragma unroll
      for (int n = 0; n < 4; ++n) { y1[j][n] = 0.0f; sq[j][n] = 0.0f; }
    int rb0 = wrow + m * 16 + rg * 4;  // local row base in tile
#pragma unroll 4
    for (int k = 0; k < 32; ++k) {
      float wv[4], wv2[4];
#pragma unroll
      for (int n = 0; n < 4; ++n) {
        wv[n] = we_lds[k * 128 + wcol + n * 16 + cl];
        wv2[n] = wv[n] * wv[n];
      }
#pragma unroll
      for (int j = 0; j < 4; ++j) {
        float xv = xe_lds[(rb0 + j) * 32 + k];
        float xv2 = xv * xv;
#pragma unroll
        for (int n = 0; n < 4; ++n) {
          y1[j][n] = fmaf(xv, wv[n], y1[j][n]);
          sq[j][n] = fmaf(xv2, wv2[n], sq[j][n]);
        }
      }
    }
    // apply gate + store  (C/D layout: col = lane&15, row = (lane>>4)*4 + j  [m89])
#pragma unroll
    for (int n = 0; n < 4; ++n) {
      int c = col0 + wcol + n * 16 + cl;
      float bv = bias[c];
#pragma unroll
      for (int j = 0; j < 4; ++j) {
        float v = acc[m][n][j] + bv;
        float y1v = y1[j][n] + bv;
        unsigned char p = gate_passed(y1v, sq[j][n], sw, sb);
        int r = row0 + wrow + m * 16 + rg * 4 + j;
        out[(size_t)r * N_DIM + c] = p ? 0.0f : v;
      }
    }
  }
}

// ---------------- fp32 fallback (only if ws_size too small) ----------------
__device__ __forceinline__ void stats4x4(const float* __restrict__ x,
                                         const float* __restrict__ w,
                                         int r0, int c0,
                                         float (&y1)[4][4], float (&sq)[4][4]) {
#pragma unroll
  for (int i = 0; i < 4; ++i)
#pragma unroll
    for (int j = 0; j < 4; ++j) { y1[i][j] = 0.0f; sq[i][j] = 0.0f; }
#pragma unroll
  for (int kc = 0; kc < 8; ++kc) {
    float4 xa[4], wa[4], x2[4], w2[4];
#pragma unroll
    for (int i = 0; i < 4; ++i)
      xa[i] = *reinterpret_cast<const float4*>(x + (size_t)(r0 + i) * K_DIM + kc * 4);
#pragma unroll
    for (int j = 0; j < 4; ++j)
      wa[j] = *reinterpret_cast<const float4*>(w + (size_t)(c0 + j) * K_DIM + kc * 4);
#pragma unroll
    for (int i = 0; i < 4; ++i)
      x2[i] = make_float4(xa[i].x * xa[i].x, xa[i].y * xa[i].y,
                          xa[i].z * xa[i].z, xa[i].w * xa[i].w);
#pragma unroll
    for (int j = 0; j < 4; ++j)
      w2[j] = make_float4(wa[j].x * wa[j].x, wa[j].y * wa[j].y,
                          wa[j].z * wa[j].z, wa[j].w * wa[j].w);
#pragma unroll
    for (int i = 0; i < 4; ++i)
#pragma unroll
      for (int j = 0; j < 4; ++j) {
        float a = y1[i][j];
        a = fmaf(xa[i].x, wa[j].x, a);
        a = fmaf(xa[i].y, wa[j].y, a);
        a = fmaf(xa[i].z, wa[j].z, a);
        a = fmaf(xa[i].w, wa[j].w, a);
        y1[i][j] = a;
        float b = sq[i][j];
        b = fmaf(x2[i].x, w2[j].x, b);
        b = fmaf(x2[i].y, w2[j].y, b);
        b = fmaf(x2[i].z, w2[j].z, b);
        b = fmaf(x2[i].w, w2[j].w, b);
        sq[i][j] = b;
      }
  }
}

__global__ void fallback_gemm_kernel(const float* __restrict__ x, const float* __restrict__ wgt,
                                     const float* __restrict__ bias, const float* __restrict__ swp,
                                     const float* __restrict__ sbp, float* __restrict__ out) {
  __shared__ float xs[64][36], ws2[64][36];
  int t = threadIdx.x;
  int tr = t >> 4, tc = t & 15;
  int r0 = blockIdx.x * 64, c0 = blockIdx.y * 64;
  float acc[4][4];
#pragma unroll
  for (int i = 0; i < 4; ++i)
#pragma unroll
    for (int j = 0; j < 4; ++j) acc[i][j] = 0.0f;

#pragma unroll 1
  for (int kt = 0; kt < K_DIM / 32; ++kt) {
#pragma unroll
    for (int i = 0; i < 2; ++i) {
      int idx = t + 256 * i;
      int row = idx >> 3;
      int kk = (idx & 7) * 4;
      *reinterpret_cast<float4*>(&xs[row][kk]) =
          *reinterpret_cast<const float4*>(x + (size_t)(r0 + row) * K_DIM + kt * 32 + kk);
      *reinterpret_cast<float4*>(&ws2[row][kk]) =
          *reinterpret_cast<const float4*>(wgt + (size_t)(c0 + row) * K_DIM + kt * 32 + kk);
    }
    __syncthreads();
#pragma unroll 4
    for (int k = 0; k < 32; ++k) {
      float xv[4], wv[4];
#pragma unroll
      for (int i = 0; i < 4; ++i) { xv[i] = xs[tr * 4 + i][k]; wv[i] = ws2[tc * 4 + i][k]; }
#pragma unroll
      for (int i = 0; i < 4; ++i)
#pragma unroll
        for (int j = 0; j < 4; ++j) acc[i][j] = fmaf(xv[i], wv[j], acc[i][j]);
    }
    __syncthreads();
  }

  float y1[4][4], sq[4][4];
  stats4x4(x, wgt, r0 + tr * 4, c0 + tc * 4, y1, sq);
  float sw = *swp, sb = *sbp;
#pragma unroll
  for (int i = 0; i < 4; ++i)
#pragma unroll
    for (int j = 0; j < 4; ++j) {
      int r = r0 + tr * 4 + i, c = c0 + tc * 4 + j;
      float bv = bias[c];
      unsigned char p = gate_passed(y1[i][j] + bv, sq[i][j], sw, sb);
      out[(size_t)r * N_DIM + c] = p ? 0.0f : (acc[i][j] + bv);
    }
}

extern "C" void kernel_launch(void* const* d_in, const int* in_sizes, int n_in,
                              void* d_out, int out_size, void* d_ws, size_t ws_size,
                              hipStream_t stream) {
  (void)in_sizes; (void)n_in; (void)out_size;
  const float* x    = (const float*)d_in[0];
  const float* wgt  = (const float*)d_in[1];
  const float* bias = (const float*)d_in[2];
  const float* swp  = (const float*)d_in[3];
  const float* sbp  = (const float*)d_in[4];
  float* out = (float*)d_out;

  const size_t xf_off = 0;
  const size_t wf_off = xf_off + (size_t)M_DIM * K_DIM * 2;    // 16 MB
  const size_t xe_off = wf_off + (size_t)N_DIM * K_DIM * 2;    // 48 MB
  const size_t we_off = xe_off + (size_t)M_DIM * 32 * 4;       // +512 KB
  const size_t need   = we_off + (size_t)N_DIM * 32 * 4;       // +1 MB

  if (ws_size >= need) {
    unsigned short* xf = (unsigned short*)((char*)d_ws + xf_off);
    unsigned short* wf = (unsigned short*)((char*)d_ws + wf_off);
    float* xe = (float*)((char*)d_ws + xe_off);
    float* we = (float*)((char*)d_ws + we_off);

    int n4x = M_DIM * K_DIM / 4;
    int n4tot = n4x + N_DIM * K_DIM / 4;
    hipLaunchKernelGGL(cvt_f16_fused_kernel, dim3(2048), dim3(256), 0, stream,
                       x, wgt, xf, wf, xe, we, n4x, n4tot);
    hipLaunchKernelGGL(gemm_f16_kernel, dim3(2048), dim3(256), 0, stream,
                       xf, wf, xe, we, bias, swp, sbp, out);
  } else {
    hipLaunchKernelGGL(fallback_gemm_kernel, dim3(M_DIM / 64, N_DIM / 64), dim3(256), 0, stream,
                       x, wgt, bias, swp, sbp, out);
  }
}